// Round 2
// baseline (878.614 us; speedup 1.0000x reference)
//
#include <hip/hip_runtime.h>
#include <hip/hip_bf16.h>
#include <stdint.h>

// B=64, C=256, H=W=64, 3x3 SAME conv, per-sample per-tap softmax mask.
// Implicit GEMM per sample: M=256(o), N=4096(y,x), K=2304(tap*256+i), bf16 MFMA.
// Round 2: counted-vmcnt pipeline (T4). 3 LDS buffers, 2-deep gld_lds prefetch,
// raw s_barrier + s_waitcnt vmcnt(8) (never drain to 0 in the main loop).
// Mask folded via telescoping accumulator rescale (round-1, verified).

typedef __hip_bfloat16 bf16;
using frag_ab = __attribute__((ext_vector_type(8))) short;  // 8 bf16 (4 VGPRs)
using frag_cd = __attribute__((ext_vector_type(4))) float;  // 4 fp32

#define AS1 __attribute__((address_space(1)))
#define AS3 __attribute__((address_space(3)))

#define NB 64
#define NC 256
#define NH 64
#define NW 64
#define HP 66
#define WP 66
#define KTOT 2304           // 9 * 256
#define XP_ELEMS ((size_t)NB * HP * WP * NC)
#define WT_ELEMS ((size_t)NC * KTOT)                   // 589,824 bf16 = 1.18 MB

__device__ __forceinline__ void gld_lds16(const void* g, void* l) {
    __builtin_amdgcn_global_load_lds((const AS1 void*)g, (AS3 void*)l, 16, 0, 0);
}

// ---- prepass 1: softmax over 9 taps per sample ----
__global__ void softmax_kernel(const float* __restrict__ act, float* __restrict__ mask) {
    int b = threadIdx.x;
    if (b < NB) {
        float v[9], mx = -1e30f;
        #pragma unroll
        for (int i = 0; i < 9; i++) { v[i] = act[b * 9 + i]; mx = fmaxf(mx, v[i]); }
        float s = 0.f;
        #pragma unroll
        for (int i = 0; i < 9; i++) { v[i] = expf(v[i] - mx); s += v[i]; }
        float inv = 1.f / s;
        #pragma unroll
        for (int i = 0; i < 9; i++) mask[b * 9 + i] = v[i] * inv;
    }
}

// ---- prepass 2: transpose w [o][i][tap] f32 -> Wt [o][tap][i] bf16 ----
__global__ __launch_bounds__(256) void wt_kernel(const float* __restrict__ w,
                                                 bf16* __restrict__ Wt) {
    int o = blockIdx.x;
    int t = threadIdx.x;
    __shared__ alignas(16) bf16 buf[KTOT];
    #pragma unroll
    for (int j = 0; j < 9; j++) {
        int idx = j * 256 + t;                 // flat within o-slice: i*9+tap
        float v = w[(size_t)o * KTOT + idx];
        int i = idx / 9, tap = idx - i * 9;
        buf[tap * 256 + i] = __float2bfloat16(v);
    }
    __syncthreads();
    const uint4* s = (const uint4*)buf;        // 288 chunks of 16B
    uint4* dst = (uint4*)(Wt + (size_t)o * KTOT);
    dst[t] = s[t];
    if (t < 32) dst[256 + t] = s[256 + t];
}

// ---- prepass 3: zero the pad border of Xp [b][66][66][256] ----
__global__ __launch_bounds__(256) void border_kernel(bf16* __restrict__ Xp) {
    int id = blockIdx.x * 256 + threadIdx.x;
    int ch = id & 31;
    int px = (id >> 5) % 260;
    int b  = (id >> 5) / 260;
    int y, x;
    if (px < 66)       { y = 0;  x = px; }
    else if (px < 132) { y = 65; x = px - 66; }
    else { int e = px - 132; y = 1 + (e >> 1); x = (e & 1) * 65; }
    bf16* dst = Xp + (((size_t)b * HP + y) * WP + x) * NC + ch * 8;
    uint4 z; z.x = 0; z.y = 0; z.z = 0; z.w = 0;
    *(uint4*)dst = z;
}

// ---- prepass 4: NCHW fp32 -> padded NHWC bf16 via LDS transpose ----
__global__ __launch_bounds__(256) void pad_kernel(const float* __restrict__ inp,
                                                  bf16* __restrict__ Xp) {
    int bid = blockIdx.x;                  // b*256 + y*4 + cb
    int cb = bid & 3;
    int y  = (bid >> 2) & 63;
    int b  = bid >> 8;
    __shared__ bf16 tile[64][66];          // [x][c], pad 66
    int t = threadIdx.x;
    int xp = (t & 31) * 2, tr = t >> 5;    // tr in 0..7
    const float* src = inp + (((size_t)b * NC + cb * 64) * NH + y) * NW + xp;
    #pragma unroll
    for (int ci = 0; ci < 4; ci++) {
        int c = tr * 8 + ci * 2;
        float2 v0 = *(const float2*)(src + (size_t)c * (NH * NW));
        float2 v1 = *(const float2*)(src + (size_t)(c + 1) * (NH * NW));
        union { bf16 h[2]; uint u; } p0, p1;
        p0.h[0] = __float2bfloat16(v0.x); p0.h[1] = __float2bfloat16(v1.x);
        p1.h[0] = __float2bfloat16(v0.y); p1.h[1] = __float2bfloat16(v1.y);
        *(uint*)&tile[xp][c]     = p0.u;
        *(uint*)&tile[xp + 1][c] = p1.u;
    }
    __syncthreads();
    #pragma unroll
    for (int pp = 0; pp < 2; pp++) {
        int x = pp * 32 + (t >> 3);
        int s = t & 7;
        uint u0 = *(const uint*)&tile[x][s * 8 + 0];
        uint u1 = *(const uint*)&tile[x][s * 8 + 2];
        uint u2 = *(const uint*)&tile[x][s * 8 + 4];
        uint u3 = *(const uint*)&tile[x][s * 8 + 6];
        uint4 val; val.x = u0; val.y = u1; val.z = u2; val.w = u3;
        bf16* dst = Xp + (((size_t)b * HP + (y + 1)) * WP + (x + 1)) * NC + cb * 64 + s * 8;
        *(uint4*)dst = val;
    }
}

// ---- main GEMM: k-chunk rotation swizzle + 3-buffer counted-vmcnt pipeline ----
// Swizzle (unchanged, verified): chunk c of LDS row R holds logical k-chunk
// (c - (R>>1)) & 3. Staging lane l loads logical chunk ((l&3) - ((l>>3)&3)) & 3;
// frag read lane l reads stored chunk ((l>>4) + ((l>>1)&3)) & 3 -> 2-way (free).
//
// Pipeline per step s (72 steps = 9 taps x 8 kk):
//   A: issue 4 gld_lds for step s+2 into buf[(s+2)%3]  (== buf read at s-1,
//      safe: all waves passed the s-1 trailing barrier)
//   B: s_waitcnt vmcnt(8)  -- own loads for buf[s%3] retired (in-order vmcnt);
//      s_barrier            -- ALL waves' buf[s%3] staging now visible
//   C: ds_read frags from buf[s%3]; MFMA (compiler inserts lgkmcnt)
//   D: sched_barrier(0)     -- pin MFMAs (rule #18: they'd sink past asm)
//      s_barrier            -- all waves done reading buf[s%3]
// Tail (last 2 steps) drains vmcnt 4 -> 0. No vmcnt(0) in the main loop.
__global__ __launch_bounds__(256) void gemm_kernel(const bf16* __restrict__ Wt,
                                                   const float* __restrict__ mask,
                                                   const bf16* __restrict__ Xp,
                                                   float* __restrict__ out) {
    int bid = blockIdx.x;
    int ntl = bid & 31;         // 32 N-tiles (2 rows x 64 cols each)
    int mt = (bid >> 5) & 1;    // 2 M-tiles of 128 o-channels
    int b  = bid >> 6;          // sample

    __shared__ bf16 As[3][128 * 32];   // [buf][o][k] rows of 64B
    __shared__ bf16 Bs[3][128 * 32];   // [buf][n][k] rows of 64B

    int t = threadIdx.x;
    int w = t >> 6;
    int l = t & 63;

    int so = w * 16 + (l >> 2);                    // staged row 0..63
    int sq = ((l & 3) - ((l >> 3) & 3)) & 3;       // swizzled logical k-chunk
    int sk = sq * 8;                               // element offset

    int ldsw = w * 1024;                           // staging byte offset in buffer

    const bf16* wrow = Wt + (size_t)(mt * 128 + so) * KTOT + sk;
    const bf16* xbase = Xp + (size_t)b * HP * WP * NC;
    int vb = so * NC + sk;

    int wm = w >> 1, wn = w & 1;
    int lm = l & 15;
    int lkq = (((l >> 4) + ((l >> 1) & 3)) & 3) * 8;   // swizzled frag chunk

    frag_cd acc[4][4];
    #pragma unroll
    for (int r = 0; r < 4; r++)
        #pragma unroll
        for (int c = 0; c < 4; c++)
            #pragma unroll
            for (int q = 0; q < 4; q++) acc[r][c][q] = 0.f;

    int apoff = (wm * 64 + lm) * 32 + lkq;
    int bpoff = (wn * 64 + lm) * 32 + lkq;

    // stage step u into the buffer at byte offset offStg.
    // A-side address is monotone: wrow + u*32 (since tap*256 + kk*32 == u*32).
    auto stage = [&](int u, int offStg) {
        int utap = u >> 3;
        int ukk  = u & 7;
        int dy = utap / 3;                 // wave-uniform scalar math
        int dx = utap - 3 * dy;
        const bf16* a0 = wrow + u * 32;
        const bf16* b0 = xbase + (((ntl * 2 + dy) * WP) + dx) * NC + vb + ukk * 32;
        char* dA = (char*)As + offStg + ldsw;
        char* dB = (char*)Bs + offStg + ldsw;
        gld_lds16(a0,             dA);
        gld_lds16(a0 + 64 * KTOT, dA + 4096);
        gld_lds16(b0,             dB);
        gld_lds16(b0 + WP * NC,   dB + 4096);
    };

    // ---- prologue: stage steps 0 and 1 ----
    stage(0, 0);
    stage(1, 8192);

    int offCur = 0, offNxt = 8192, offStg = 16384;
    float mprev = 0.f;

    #pragma unroll 1
    for (int tap = 0; tap < 8; tap++) {
        float mcur = mask[b * 9 + tap];
        if (tap) {
            float rsc = mprev / mcur;                       // telescoping rescale
            #pragma unroll
            for (int r = 0; r < 4; r++)
                #pragma unroll
                for (int c = 0; c < 4; c++)
                    #pragma unroll
                    for (int q = 0; q < 4; q++) acc[r][c][q] *= rsc;
        }
        mprev = mcur;

        #pragma unroll
        for (int kk = 0; kk < 8; kk++) {
            stage(tap * 8 + kk + 2, offStg);
            asm volatile("s_waitcnt vmcnt(8)" ::: "memory");
            asm volatile("s_barrier" ::: "memory");

            const bf16* ap = (const bf16*)((const char*)As + offCur) + apoff;
            const bf16* bp = (const bf16*)((const char*)Bs + offCur) + bpoff;
            frag_ab af[4], bfr[4];
            #pragma unroll
            for (int r = 0; r < 4; r++) af[r]  = *(const frag_ab*)(ap + r * 16 * 32);
            #pragma unroll
            for (int c = 0; c < 4; c++) bfr[c] = *(const frag_ab*)(bp + c * 16 * 32);
            #pragma unroll
            for (int r = 0; r < 4; r++)
                #pragma unroll
                for (int c = 0; c < 4; c++)
                    acc[r][c] = __builtin_amdgcn_mfma_f32_16x16x32_bf16(
                        af[r], bfr[c], acc[r][c], 0, 0, 0);

            __builtin_amdgcn_sched_barrier(0);
            asm volatile("s_barrier" ::: "memory");

            int tmp = offStg; offStg = offCur; offCur = offNxt; offNxt = tmp;
        }
    }

    // ---- tail: tap = 8, drain vmcnt 8 -> 4 -> 0 ----
    {
        float mcur = mask[b * 9 + 8];
        float rsc = mprev / mcur;
        #pragma unroll
        for (int r = 0; r < 4; r++)
            #pragma unroll
            for (int c = 0; c < 4; c++)
                #pragma unroll
                for (int q = 0; q < 4; q++) acc[r][c][q] *= rsc;
        mprev = mcur;

        #pragma unroll
        for (int kk = 0; kk < 8; kk++) {
            if (kk < 6) {
                stage(66 + kk, offStg);
                asm volatile("s_waitcnt vmcnt(8)" ::: "memory");
            } else if (kk == 6) {
                asm volatile("s_waitcnt vmcnt(4)" ::: "memory");
            } else {
                asm volatile("s_waitcnt vmcnt(0)" ::: "memory");
            }
            asm volatile("s_barrier" ::: "memory");

            const bf16* ap = (const bf16*)((const char*)As + offCur) + apoff;
            const bf16* bp = (const bf16*)((const char*)Bs + offCur) + bpoff;
            frag_ab af[4], bfr[4];
            #pragma unroll
            for (int r = 0; r < 4; r++) af[r]  = *(const frag_ab*)(ap + r * 16 * 32);
            #pragma unroll
            for (int c = 0; c < 4; c++) bfr[c] = *(const frag_ab*)(bp + c * 16 * 32);
            #pragma unroll
            for (int r = 0; r < 4; r++)
                #pragma unroll
                for (int c = 0; c < 4; c++)
                    acc[r][c] = __builtin_amdgcn_mfma_f32_16x16x32_bf16(
                        af[r], bfr[c], acc[r][c], 0, 0, 0);

            __builtin_amdgcn_sched_barrier(0);
            asm volatile("s_barrier" ::: "memory");

            int tmp = offStg; offStg = offCur; offCur = offNxt; offNxt = tmp;
        }
    }

    float m8 = mprev;
    int col = lm;
    int rq = (l >> 4) * 4;
    #pragma unroll
    for (int r = 0; r < 4; r++) {
        #pragma unroll
        for (int c = 0; c < 4; c++) {
            int m = mt * 128 + wm * 64 + r * 16 + rq;
            int n = wn * 64 + c * 16 + col;
            float* po = out + ((size_t)(b * 256 + m)) * (NH * NW) + ntl * 128 + n;
            #pragma unroll
            for (int q = 0; q < 4; q++) po[(size_t)q * (NH * NW)] = m8 * acc[r][c][q];
        }
    }
}

__global__ void diag_kernel(float* out) { out[threadIdx.x] = 12345.0f; }

extern "C" void kernel_launch(void* const* d_in, const int* in_sizes, int n_in,
                              void* d_out, int out_size, void* d_ws, size_t ws_size,
                              hipStream_t stream) {
    const float* inp = (const float*)d_in[0];
    const float* act = (const float*)d_in[1];
    const float* wgt = (const float*)d_in[2];
    float* out = (float*)d_out;

    size_t MASK_OFF = 0;
    size_t WT_OFF = 4096;
    size_t XP_OFF = WT_OFF + WT_ELEMS * sizeof(bf16);   // 4096 + 1,179,648
    size_t NEED  = XP_OFF + XP_ELEMS * sizeof(bf16);    // ~144 MB

    if (ws_size < NEED) {
        diag_kernel<<<1, 256, 0, stream>>>(out);
        return;
    }

    float* mask = (float*)((char*)d_ws + MASK_OFF);
    bf16* Wt = (bf16*)((char*)d_ws + WT_OFF);           // persistent (A operand)
    bf16* Xp = (bf16*)((char*)d_ws + XP_OFF);

    softmax_kernel<<<1, 64, 0, stream>>>(act, mask);
    wt_kernel<<<NC, 256, 0, stream>>>(wgt, Wt);
    border_kernel<<<(NB * 260 * 32) / 256, 256, 0, stream>>>(Xp);
    pad_kernel<<<NB * NH * 4, 256, 0, stream>>>(inp, Xp);
    gemm_kernel<<<NB * 2 * 32, 256, 0, stream>>>(Wt, mask, Xp, out);
}

// Round 3
// 700.555 us; speedup vs baseline: 1.2542x; 1.2542x over previous
//
#include <hip/hip_runtime.h>
#include <hip/hip_bf16.h>
#include <stdint.h>
#include <math.h>

// B=64, C=256, H=W=64, 3x3 SAME conv, per-sample per-tap softmax mask.
// Implicit GEMM per sample: M=256(o), N=4096(y,x), K=2304(tap*256+i), bf16 MFMA.
// Round 3: 256x256 8-phase-style schedule (T3+T4+T5+T1), BK=64, 8 waves,
// 128 KB double-buffered LDS, counted vmcnt(4) (never 0 in main loop).
// Mask folded via telescoping accumulator rescale; softmax computed in-block.

typedef __hip_bfloat16 bf16;
using frag_ab = __attribute__((ext_vector_type(8))) short;  // 8 bf16 (4 VGPRs)
using frag_cd = __attribute__((ext_vector_type(4))) float;  // 4 fp32

#define AS1 __attribute__((address_space(1)))
#define AS3 __attribute__((address_space(3)))

#define NB 64
#define NC 256
#define NH 64
#define NW 64
#define HP 66
#define WP 66
#define KTOT 2304           // 9 * 256
#define XP_ELEMS ((size_t)NB * HP * WP * NC)
#define WT_ELEMS ((size_t)NC * KTOT)                   // 589,824 bf16 = 1.18 MB

// Dynamic LDS map (131200 B):
//   As: [2 buf][256 rows][128 B]  @ 0       (65536)
//   Bs: [2 buf][256 pix ][128 B]  @ 65536   (65536)
//   rs: 10 floats                 @ 131136  (rs[1..8]=m[t-1]/m[t], rs[9]=m[8])
#define BS_OFF 65536
#define RS_OFF 131136
#define SMEM_BYTES 131200

__device__ __forceinline__ void gld_lds16(const void* g, void* l) {
    __builtin_amdgcn_global_load_lds((const AS1 void*)g, (AS3 void*)l, 16, 0, 0);
}

// ---- prepass: transpose w [o][i][tap] f32 -> Wt [o][tap][i] bf16 ----
__global__ __launch_bounds__(256) void wt_kernel(const float* __restrict__ w,
                                                 bf16* __restrict__ Wt) {
    int o = blockIdx.x;
    int t = threadIdx.x;
    __shared__ alignas(16) bf16 buf[KTOT];
    #pragma unroll
    for (int j = 0; j < 9; j++) {
        int idx = j * 256 + t;                 // flat within o-slice: i*9+tap
        float v = w[(size_t)o * KTOT + idx];
        int i = idx / 9, tap = idx - i * 9;
        buf[tap * 256 + i] = __float2bfloat16(v);
    }
    __syncthreads();
    const uint4* s = (const uint4*)buf;        // 288 chunks of 16B
    uint4* dst = (uint4*)(Wt + (size_t)o * KTOT);
    dst[t] = s[t];
    if (t < 32) dst[256 + t] = s[256 + t];
}

// ---- prepass: zero the pad border of Xp [b][66][66][256] ----
__global__ __launch_bounds__(256) void border_kernel(bf16* __restrict__ Xp) {
    int id = blockIdx.x * 256 + threadIdx.x;
    int ch = id & 31;
    int px = (id >> 5) % 260;
    int b  = (id >> 5) / 260;
    int y, x;
    if (px < 66)       { y = 0;  x = px; }
    else if (px < 132) { y = 65; x = px - 66; }
    else { int e = px - 132; y = 1 + (e >> 1); x = (e & 1) * 65; }
    bf16* dst = Xp + (((size_t)b * HP + y) * WP + x) * NC + ch * 8;
    uint4 z; z.x = 0; z.y = 0; z.z = 0; z.w = 0;
    *(uint4*)dst = z;
}

// ---- prepass: NCHW fp32 -> padded NHWC bf16 via LDS transpose ----
__global__ __launch_bounds__(256) void pad_kernel(const float* __restrict__ inp,
                                                  bf16* __restrict__ Xp) {
    int bid = blockIdx.x;                  // b*256 + y*4 + cb
    int cb = bid & 3;
    int y  = (bid >> 2) & 63;
    int b  = bid >> 8;
    __shared__ bf16 tile[64][66];          // [x][c], pad 66
    int t = threadIdx.x;
    int xp = (t & 31) * 2, tr = t >> 5;    // tr in 0..7
    const float* src = inp + (((size_t)b * NC + cb * 64) * NH + y) * NW + xp;
    #pragma unroll
    for (int ci = 0; ci < 4; ci++) {
        int c = tr * 8 + ci * 2;
        float2 v0 = *(const float2*)(src + (size_t)c * (NH * NW));
        float2 v1 = *(const float2*)(src + (size_t)(c + 1) * (NH * NW));
        union { bf16 h[2]; uint u; } p0, p1;
        p0.h[0] = __float2bfloat16(v0.x); p0.h[1] = __float2bfloat16(v1.x);
        p1.h[0] = __float2bfloat16(v0.y); p1.h[1] = __float2bfloat16(v1.y);
        *(uint*)&tile[xp][c]     = p0.u;
        *(uint*)&tile[xp + 1][c] = p1.u;
    }
    __syncthreads();
    #pragma unroll
    for (int pp = 0; pp < 2; pp++) {
        int x = pp * 32 + (t >> 3);
        int s = t & 7;
        uint u0 = *(const uint*)&tile[x][s * 8 + 0];
        uint u1 = *(const uint*)&tile[x][s * 8 + 2];
        uint u2 = *(const uint*)&tile[x][s * 8 + 4];
        uint u3 = *(const uint*)&tile[x][s * 8 + 6];
        uint4 val; val.x = u0; val.y = u1; val.z = u2; val.w = u3;
        bf16* dst = Xp + (((size_t)b * HP + (y + 1)) * WP + (x + 1)) * NC + cb * 64 + s * 8;
        *(uint4*)dst = val;
    }
}

// ---- main GEMM: 256x256 tile, BK=64, 8 waves, 4-phase K-tile schedule ----
//
// LDS rows are 128 B (64 bf16). Rotation swizzle: logical 16B chunk q of row R
// is stored at position p=(q+R)&7. Staging lane v (dest pos v&7, row base+(v>>3),
// R==v>>3 mod 8) loads q=((v&7)-(v>>3))&7 -> per-lane constant.
// Frag read (row R = const+lm, q = ks*4+lq): p=((ks*4+lq+(lm&7))&7) -> per-lane
// constant per ks; 8 lanes per 16B-position -> perfectly bank-balanced.
//
// Staging chunks per K-tile, issue order = need order:
//   S0 = A-fronts (rows 0-63,128-191)   needed ph0
//   S1 = B-fronts (pix 0-31,64-95,128-159,192-223) needed ph0
//   S2 = B-backs                         needed ph1
//   S3 = A-backs                         needed ph2
// During K-tile t (buf=t&1) stage S0..S3 of t+1 into buf^1, one per phase.
// Outstanding-set invariant at each vmcnt(4): exactly the 2 newest chunks
// remain in flight; the chunk needed by the next phase has landed.
__global__ __launch_bounds__(512, 2) void gemm_kernel(const bf16* __restrict__ Wt,
                                                      const float* __restrict__ act,
                                                      const bf16* __restrict__ Xp,
                                                      float* __restrict__ out) {
    extern __shared__ char sm[];

    // T1: bijective XCD swizzle (1024 wgs, 8 XCDs, 128 contiguous per XCD)
    int bid = blockIdx.x;
    int wg = (bid & 7) * 128 + (bid >> 3);
    int b  = wg >> 4;           // sample
    int nt = wg & 15;           // pixel-row-group (4 rows x 64 cols = 256 pixels)
    int ybase = nt * 4;

    int tid = threadIdx.x;
    int w = tid >> 6, l = tid & 63;
    int wm = w >> 2, wn = w & 3;           // 2M x 4N wave grid
    int lm = l & 15, lq = l >> 4;

    // softmax + telescoping ratios (thread 0, once per block)
    if (tid == 0) {
        float m[9], mx = -1e30f;
        #pragma unroll
        for (int i = 0; i < 9; i++) { m[i] = act[b * 9 + i]; mx = fmaxf(mx, m[i]); }
        float s = 0.f;
        #pragma unroll
        for (int i = 0; i < 9; i++) { m[i] = expf(m[i] - mx); s += m[i]; }
        float inv = 1.f / s;
        #pragma unroll
        for (int i = 0; i < 9; i++) m[i] *= inv;
        float* rs = (float*)(sm + RS_OFF);
        #pragma unroll
        for (int i = 1; i < 9; i++) rs[i] = m[i - 1] / m[i];
        rs[9] = m[8];
    }

    // frag-read per-lane constants
    int pA0 = ((lq + (lm & 7)) & 7) * 16;          // ks=0 chunk position (bytes)
    int pA1 = ((lq + 4 + (lm & 7)) & 7) * 16;      // ks=1
    int aRdRow = (wm * 128 + lm) * 128;            // A row byte offset
    int bRdRow = (wn * 64 + lm) * 128;             // B row byte offset

    // staging per-lane constants
    int qs = ((l & 7) - (l >> 3)) & 7;             // source chunk (pre-rotation)
    int qe = qs * 8;                               // elems
    int srcAf[2], srcAb[2], srcBf[2], srcBb[2];    // elem offsets
    int dAf[2], dAb[2], dBf[2], dBb[2];            // LDS byte offsets (in-buf)
    #pragma unroll
    for (int r = 0; r < 2; r++) {
        int j  = w * 16 + r * 8 + (l >> 3);
        int j0 = w * 16 + r * 8;
        int RAf = j  + ((j  < 64) ? 0 : 64);
        int R0f = j0 + ((j0 < 64) ? 0 : 64);
        int RAb = j  + ((j  < 64) ? 64 : 128);
        int R0b = j0 + ((j0 < 64) ? 64 : 128);
        srcAf[r] = RAf * KTOT + qe;
        srcAb[r] = RAb * KTOT + qe;
        dAf[r] = R0f * 128;
        dAb[r] = R0b * 128;
        int pixf  = ((j  >> 5) << 6) + (j  & 31);
        int pix0f = ((j0 >> 5) << 6) + (j0 & 31);
        srcBf[r] = ((b * HP + ybase + (pixf >> 6)) * WP + (pixf & 63)) * NC + qe;
        dBf[r] = BS_OFF + pix0f * 128;
        int pixb = pixf + 32;
        srcBb[r] = ((b * HP + ybase + (pixb >> 6)) * WP + (pixb & 63)) * NC + qe;
        dBb[r] = BS_OFF + (pix0f + 32) * 128;
    }

#define STAGE_A_F(SAE, BUFN) { _Pragma("unroll") for (int r = 0; r < 2; r++) \
    gld_lds16(Wt + srcAf[r] + (SAE), sm + (BUFN) * 32768 + dAf[r]); }
#define STAGE_A_B(SAE, BUFN) { _Pragma("unroll") for (int r = 0; r < 2; r++) \
    gld_lds16(Wt + srcAb[r] + (SAE), sm + (BUFN) * 32768 + dAb[r]); }
#define STAGE_B_F(SBE, BUFN) { _Pragma("unroll") for (int r = 0; r < 2; r++) \
    gld_lds16(Xp + srcBf[r] + (SBE), sm + (BUFN) * 32768 + dBf[r]); }
#define STAGE_B_B(SBE, BUFN) { _Pragma("unroll") for (int r = 0; r < 2; r++) \
    gld_lds16(Xp + srcBb[r] + (SBE), sm + (BUFN) * 32768 + dBb[r]); }

    // prologue: stage all 4 chunks of K-tile 0 into buf 0 (order = S0..S3)
    STAGE_A_F(0, 0);
    __builtin_amdgcn_sched_barrier(0);
    STAGE_B_F(0, 0);
    __builtin_amdgcn_sched_barrier(0);
    STAGE_B_B(0, 0);
    __builtin_amdgcn_sched_barrier(0);
    STAGE_A_B(0, 0);
    asm volatile("s_waitcnt lgkmcnt(0)" ::: "memory");   // rs writes visible
    asm volatile("s_waitcnt vmcnt(4)" ::: "memory");     // S0,S1 landed
    __builtin_amdgcn_s_barrier();

    frag_cd acc[8][4];                  // [mh*4+mf][nh*2+nf]
    #pragma unroll
    for (int i = 0; i < 8; i++)
        #pragma unroll
        for (int jx = 0; jx < 4; jx++)
            #pragma unroll
            for (int q = 0; q < 4; q++) acc[i][jx][q] = 0.f;

    frag_ab af[2][4], bfr[2][2];

#define LD_A(MH) { _Pragma("unroll") for (int mf = 0; mf < 4; mf++) { \
    af[0][mf] = *(const frag_ab*)(aB0 + (MH) * 8192 + mf * 2048); \
    af[1][mf] = *(const frag_ab*)(aB1 + (MH) * 8192 + mf * 2048); } }
#define LD_B(NHH) { _Pragma("unroll") for (int nf = 0; nf < 2; nf++) { \
    bfr[0][nf] = *(const frag_ab*)(bB0 + (NHH) * 4096 + nf * 2048); \
    bfr[1][nf] = *(const frag_ab*)(bB1 + (NHH) * 4096 + nf * 2048); } }
#define MM(MH, NHH) { __builtin_amdgcn_s_setprio(1); \
    _Pragma("unroll") for (int mf = 0; mf < 4; mf++) \
    _Pragma("unroll") for (int nf = 0; nf < 2; nf++) { \
        acc[(MH)*4+mf][(NHH)*2+nf] = __builtin_amdgcn_mfma_f32_16x16x32_bf16( \
            af[0][mf], bfr[0][nf], acc[(MH)*4+mf][(NHH)*2+nf], 0, 0, 0); \
        acc[(MH)*4+mf][(NHH)*2+nf] = __builtin_amdgcn_mfma_f32_16x16x32_bf16( \
            af[1][mf], bfr[1][nf], acc[(MH)*4+mf][(NHH)*2+nf], 0, 0, 0); } \
    __builtin_amdgcn_s_setprio(0); }

    #pragma unroll 1
    for (int t = 0; t < 35; ++t) {
        int buf = t & 1, bufN = buf ^ 1;
        if ((t & 3) == 0 && t) {
            float rsc = *(const float*)(sm + RS_OFF + (t >> 2) * 4);
            #pragma unroll
            for (int i = 0; i < 8; i++)
                #pragma unroll
                for (int jx = 0; jx < 4; jx++)
                    #pragma unroll
                    for (int q = 0; q < 4; q++) acc[i][jx][q] *= rsc;
        }
        int tn = t + 1;
        int sAe = tn * 64;                         // A offset for tile t+1
        int tapN = tn >> 2;
        int dyN = tapN / 3, dxN = tapN - 3 * dyN;
        int sBe = (dyN * WP + dxN) * NC + (tn & 3) * 64;

        const char* aB0 = sm + buf * 32768 + aRdRow + pA0;
        const char* aB1 = sm + buf * 32768 + aRdRow + pA1;
        const char* bB0 = sm + buf * 32768 + bRdRow + pA0;  // bRdRow includes no BS_OFF
        const char* bB1 = sm + buf * 32768 + bRdRow + pA1;
        bB0 += BS_OFF; bB1 += BS_OFF;

        // ph0: quadrant (mh0, nh0); stage S0(t+1)
        LD_A(0); LD_B(0);
        STAGE_A_F(sAe, bufN);
        MM(0, 0);
        __builtin_amdgcn_sched_barrier(0);
        asm volatile("s_waitcnt vmcnt(4)" ::: "memory");   // S2(t) landed
        __builtin_amdgcn_s_barrier();

        // ph1: (mh0, nh1); stage S1(t+1)
        LD_B(1);
        STAGE_B_F(sBe, bufN);
        MM(0, 1);
        __builtin_amdgcn_sched_barrier(0);
        asm volatile("s_waitcnt vmcnt(4)" ::: "memory");   // S3(t) landed
        __builtin_amdgcn_s_barrier();

        // ph2: (mh1, nh1); stage S2(t+1); no sync needed before ph3
        LD_A(1);
        STAGE_B_B(sBe, bufN);
        MM(1, 1);
        __builtin_amdgcn_sched_barrier(0);                 // pin S2' before S3'

        // ph3: (mh1, nh0); stage S3(t+1)
        LD_B(0);
        STAGE_A_B(sAe, bufN);
        MM(1, 0);
        __builtin_amdgcn_sched_barrier(0);
        asm volatile("s_waitcnt vmcnt(4)" ::: "memory");   // S0,S1(t+1) landed
        __builtin_amdgcn_s_barrier();
    }

    // tail: t = 35 (buf 1), no staging; drain 4 -> 2 -> 0
    {
        const char* aB0 = sm + 32768 + aRdRow + pA0;
        const char* aB1 = sm + 32768 + aRdRow + pA1;
        const char* bB0 = sm + 32768 + bRdRow + pA0 + BS_OFF;
        const char* bB1 = sm + 32768 + bRdRow + pA1 + BS_OFF;

        LD_A(0); LD_B(0);
        MM(0, 0);
        __builtin_amdgcn_sched_barrier(0);
        asm volatile("s_waitcnt vmcnt(2)" ::: "memory");   // S2(35) landed
        __builtin_amdgcn_s_barrier();

        LD_B(1);
        MM(0, 1);
        __builtin_amdgcn_sched_barrier(0);
        asm volatile("s_waitcnt vmcnt(0)" ::: "memory");   // S3(35) landed
        __builtin_amdgcn_s_barrier();

        LD_A(1);
        MM(1, 1);
        __builtin_amdgcn_sched_barrier(0);

        LD_B(0);
        MM(1, 0);
    }

    // epilogue: final scale by m[8], write C
    float m8 = *(const float*)(sm + RS_OFF + 9 * 4);
    int rqBase = lq * 4;
    #pragma unroll
    for (int mh = 0; mh < 2; mh++)
        #pragma unroll
        for (int mf = 0; mf < 4; mf++)
            #pragma unroll
            for (int nh = 0; nh < 2; nh++)
                #pragma unroll
                for (int nf = 0; nf < 2; nf++) {
                    int m = wm * 128 + mh * 64 + mf * 16 + rqBase;
                    int n = nt * 256 + wn * 64 + nh * 32 + nf * 16 + lm;
                    float* po = out + ((size_t)(b * 256 + m)) * 4096 + n;
                    frag_cd v = acc[mh * 4 + mf][nh * 2 + nf];
                    #pragma unroll
                    for (int q = 0; q < 4; q++) po[(size_t)q * 4096] = m8 * v[q];
                }
}

__global__ void diag_kernel(float* out) { out[threadIdx.x] = 12345.0f; }

extern "C" void kernel_launch(void* const* d_in, const int* in_sizes, int n_in,
                              void* d_out, int out_size, void* d_ws, size_t ws_size,
                              hipStream_t stream) {
    const float* inp = (const float*)d_in[0];
    const float* act = (const float*)d_in[1];
    const float* wgt = (const float*)d_in[2];
    float* out = (float*)d_out;

    size_t WT_OFF = 0;
    size_t XP_OFF = WT_ELEMS * sizeof(bf16);            // 1,179,648 (4K-aligned)
    size_t NEED  = XP_OFF + XP_ELEMS * sizeof(bf16);    // ~144 MB

    if (ws_size < NEED) {
        diag_kernel<<<1, 256, 0, stream>>>(out);
        return;
    }

    bf16* Wt = (bf16*)((char*)d_ws + WT_OFF);
    bf16* Xp = (bf16*)((char*)d_ws + XP_OFF);

    hipFuncSetAttribute((const void*)gemm_kernel,
                        hipFuncAttributeMaxDynamicSharedMemorySize, SMEM_BYTES);

    wt_kernel<<<NC, 256, 0, stream>>>(wgt, Wt);
    border_kernel<<<(NB * 260 * 32) / 256, 256, 0, stream>>>(Xp);
    pad_kernel<<<NB * NH * 4, 256, 0, stream>>>(inp, Xp);
    gemm_kernel<<<NB * 16, 512, SMEM_BYTES, stream>>>(Wt, act, Xp, out);
}

// Round 4
// 695.900 us; speedup vs baseline: 1.2626x; 1.0067x over previous
//
#include <hip/hip_runtime.h>
#include <hip/hip_bf16.h>
#include <stdint.h>
#include <math.h>

// B=64, C=256, H=W=64, 3x3 SAME conv, per-sample per-tap softmax mask.
// Implicit GEMM per sample: M=256(o), N=4096(y,x), K=2304(tap*256+i), bf16 MFMA.
// Round 4: deep-prefetch 4-phase schedule. All B-frags held in regs (32 ds_reads
// per wave per K-tile, was 40); staging of tile t+2 issued at ph1..ph3 of tile t
// into the CURRENTLY-READ buffer (each chunk region is last-read exactly one
// phase earlier) -> 7 phases (~1700 cyc) latency cover; ONE vmcnt(8) per K-tile.

typedef __hip_bfloat16 bf16;
using frag_ab = __attribute__((ext_vector_type(8))) short;  // 8 bf16 (4 VGPRs)
using frag_cd = __attribute__((ext_vector_type(4))) float;  // 4 fp32

#define AS1 __attribute__((address_space(1)))
#define AS3 __attribute__((address_space(3)))

#define NB 64
#define NC 256
#define NH 64
#define NW 64
#define HP 66
#define WP 66
#define KTOT 2304           // 9 * 256
#define XP_ELEMS ((size_t)NB * HP * WP * NC)
#define WT_ELEMS ((size_t)NC * KTOT)                   // 589,824 bf16 = 1.18 MB

// Dynamic LDS map (131200 B):
//   As: [2 buf][256 rows][128 B]  @ 0       (65536)
//   Bs: [2 buf][256 pix ][128 B]  @ 65536   (65536)
//   rs: 10 floats                 @ 131136  (rs[1..8]=m[t-1]/m[t], rs[9]=m[8])
#define BS_OFF 65536
#define RS_OFF 131136
#define SMEM_BYTES 131200

__device__ __forceinline__ void gld_lds16(const void* g, void* l) {
    __builtin_amdgcn_global_load_lds((const AS1 void*)g, (AS3 void*)l, 16, 0, 0);
}

// ---- prepass: transpose w [o][i][tap] f32 -> Wt [o][tap][i] bf16 ----
__global__ __launch_bounds__(256) void wt_kernel(const float* __restrict__ w,
                                                 bf16* __restrict__ Wt) {
    int o = blockIdx.x;
    int t = threadIdx.x;
    __shared__ alignas(16) bf16 buf[KTOT];
    #pragma unroll
    for (int j = 0; j < 9; j++) {
        int idx = j * 256 + t;                 // flat within o-slice: i*9+tap
        float v = w[(size_t)o * KTOT + idx];
        int i = idx / 9, tap = idx - i * 9;
        buf[tap * 256 + i] = __float2bfloat16(v);
    }
    __syncthreads();
    const uint4* s = (const uint4*)buf;        // 288 chunks of 16B
    uint4* dst = (uint4*)(Wt + (size_t)o * KTOT);
    dst[t] = s[t];
    if (t < 32) dst[256 + t] = s[256 + t];
}

// ---- prepass: zero the pad border of Xp [b][66][66][256] ----
__global__ __launch_bounds__(256) void border_kernel(bf16* __restrict__ Xp) {
    int id = blockIdx.x * 256 + threadIdx.x;
    int ch = id & 31;
    int px = (id >> 5) % 260;
    int b  = (id >> 5) / 260;
    int y, x;
    if (px < 66)       { y = 0;  x = px; }
    else if (px < 132) { y = 65; x = px - 66; }
    else { int e = px - 132; y = 1 + (e >> 1); x = (e & 1) * 65; }
    bf16* dst = Xp + (((size_t)b * HP + y) * WP + x) * NC + ch * 8;
    uint4 z; z.x = 0; z.y = 0; z.z = 0; z.w = 0;
    *(uint4*)dst = z;
}

// ---- prepass: NCHW fp32 -> padded NHWC bf16 via LDS transpose ----
__global__ __launch_bounds__(256) void pad_kernel(const float* __restrict__ inp,
                                                  bf16* __restrict__ Xp) {
    int bid = blockIdx.x;                  // b*256 + y*4 + cb
    int cb = bid & 3;
    int y  = (bid >> 2) & 63;
    int b  = bid >> 8;
    __shared__ bf16 tile[64][66];          // [x][c], pad 66
    int t = threadIdx.x;
    int xp = (t & 31) * 2, tr = t >> 5;    // tr in 0..7
    const float* src = inp + (((size_t)b * NC + cb * 64) * NH + y) * NW + xp;
    #pragma unroll
    for (int ci = 0; ci < 4; ci++) {
        int c = tr * 8 + ci * 2;
        float2 v0 = *(const float2*)(src + (size_t)c * (NH * NW));
        float2 v1 = *(const float2*)(src + (size_t)(c + 1) * (NH * NW));
        union { bf16 h[2]; uint u; } p0, p1;
        p0.h[0] = __float2bfloat16(v0.x); p0.h[1] = __float2bfloat16(v1.x);
        p1.h[0] = __float2bfloat16(v0.y); p1.h[1] = __float2bfloat16(v1.y);
        *(uint*)&tile[xp][c]     = p0.u;
        *(uint*)&tile[xp + 1][c] = p1.u;
    }
    __syncthreads();
    #pragma unroll
    for (int pp = 0; pp < 2; pp++) {
        int x = pp * 32 + (t >> 3);
        int s = t & 7;
        uint u0 = *(const uint*)&tile[x][s * 8 + 0];
        uint u1 = *(const uint*)&tile[x][s * 8 + 2];
        uint u2 = *(const uint*)&tile[x][s * 8 + 4];
        uint u3 = *(const uint*)&tile[x][s * 8 + 6];
        uint4 val; val.x = u0; val.y = u1; val.z = u2; val.w = u3;
        bf16* dst = Xp + (((size_t)b * HP + (y + 1)) * WP + (x + 1)) * NC + cb * 64 + s * 8;
        *(uint4*)dst = val;
    }
}

// ---- main GEMM: 256x256 tile, BK=64, 8 waves, deep-prefetch 4-phase ----
//
// LDS rotation swizzle (verified r3): logical 16B chunk q of row R stored at
// p=(q+R)&7. Staging lane v loads q=((v&7)-(v>>3))&7; frag read lane l reads
// p=((ks*4+lq+(lm&7))&7) -> 8 lanes per position, all banks 8-deep (optimal).
//
// Region last-read map (per tile u, buf=u&1):  S0 (A-front rows {0-63,128-191})
// @ph0; S1 (B-front pix {0-31,64-95,...}) @ph0; S2 (B-back) @ph1; S3 (A-back)
// @ph2.  Therefore stage tile u+2 chunks INTO buf u&1 at: ph1 -> S0,S1;
// ph2 -> S2; ph3 -> S3.  Each chunk has 7 phases of cover before first use.
// Loads/thread/tile = 8; ONE s_waitcnt vmcnt(8) at end of ph3 retires all of
// tile u+1's chunks exactly (newest-8 invariant). Barriers at each phase end
// order last-read vs overwrite. Tail (tiles 34,35) drains 8->4->2->0.
__global__ __launch_bounds__(512, 2) void gemm_kernel(const bf16* __restrict__ Wt,
                                                      const float* __restrict__ act,
                                                      const bf16* __restrict__ Xp,
                                                      float* __restrict__ out) {
    extern __shared__ char sm[];

    // T1: bijective XCD swizzle (1024 wgs, 8 XCDs, 128 contiguous per XCD)
    int bid = blockIdx.x;
    int wg = (bid & 7) * 128 + (bid >> 3);
    int b  = wg >> 4;           // sample
    int nt = wg & 15;           // pixel-row-group (4 rows x 64 cols = 256 pixels)
    int ybase = nt * 4;

    int tid = threadIdx.x;
    int w = tid >> 6, l = tid & 63;
    int wm = w >> 2, wn = w & 3;           // 2M x 4N wave grid
    int lm = l & 15, lq = l >> 4;

    // softmax + telescoping ratios (thread 0, once per block)
    if (tid == 0) {
        float m[9], mx = -1e30f;
        #pragma unroll
        for (int i = 0; i < 9; i++) { m[i] = act[b * 9 + i]; mx = fmaxf(mx, m[i]); }
        float s = 0.f;
        #pragma unroll
        for (int i = 0; i < 9; i++) { m[i] = expf(m[i] - mx); s += m[i]; }
        float inv = 1.f / s;
        #pragma unroll
        for (int i = 0; i < 9; i++) m[i] *= inv;
        float* rs = (float*)(sm + RS_OFF);
        #pragma unroll
        for (int i = 1; i < 9; i++) rs[i] = m[i - 1] / m[i];
        rs[9] = m[8];
    }

    // frag-read per-lane constants
    int pA0 = ((lq + (lm & 7)) & 7) * 16;          // ks=0 chunk position (bytes)
    int pA1 = ((lq + 4 + (lm & 7)) & 7) * 16;      // ks=1
    int aRdRow = (wm * 128 + lm) * 128;            // A row byte offset
    int bRdRow = (wn * 64 + lm) * 128;             // B row byte offset

    // staging per-lane constants
    int qs = ((l & 7) - (l >> 3)) & 7;             // source chunk (pre-rotation)
    int qe = qs * 8;                               // elems
    int srcAf[2], srcAb[2], srcBf[2], srcBb[2];    // elem offsets
    int dAf[2], dAb[2], dBf[2], dBb[2];            // LDS byte offsets (in-buf)
    #pragma unroll
    for (int r = 0; r < 2; r++) {
        int j  = w * 16 + r * 8 + (l >> 3);
        int j0 = w * 16 + r * 8;
        int RAf = j  + ((j  < 64) ? 0 : 64);
        int R0f = j0 + ((j0 < 64) ? 0 : 64);
        int RAb = j  + ((j  < 64) ? 64 : 128);
        int R0b = j0 + ((j0 < 64) ? 64 : 128);
        srcAf[r] = RAf * KTOT + qe;
        srcAb[r] = RAb * KTOT + qe;
        dAf[r] = R0f * 128;
        dAb[r] = R0b * 128;
        int pixf  = ((j  >> 5) << 6) + (j  & 31);
        int pix0f = ((j0 >> 5) << 6) + (j0 & 31);
        srcBf[r] = ((b * HP + ybase + (pixf >> 6)) * WP + (pixf & 63)) * NC + qe;
        dBf[r] = BS_OFF + pix0f * 128;
        int pixb = pixf + 32;
        srcBb[r] = ((b * HP + ybase + (pixb >> 6)) * WP + (pixb & 63)) * NC + qe;
        dBb[r] = BS_OFF + (pix0f + 32) * 128;
    }

#define STAGE_A_F(SAE, BUFN) { _Pragma("unroll") for (int r = 0; r < 2; r++) \
    gld_lds16(Wt + srcAf[r] + (SAE), sm + (BUFN) * 32768 + dAf[r]); }
#define STAGE_A_B(SAE, BUFN) { _Pragma("unroll") for (int r = 0; r < 2; r++) \
    gld_lds16(Wt + srcAb[r] + (SAE), sm + (BUFN) * 32768 + dAb[r]); }
#define STAGE_B_F(SBE, BUFN) { _Pragma("unroll") for (int r = 0; r < 2; r++) \
    gld_lds16(Xp + srcBf[r] + (SBE), sm + (BUFN) * 32768 + dBf[r]); }
#define STAGE_B_B(SBE, BUFN) { _Pragma("unroll") for (int r = 0; r < 2; r++) \
    gld_lds16(Xp + srcBb[r] + (SBE), sm + (BUFN) * 32768 + dBb[r]); }

    // ---- prologue: stage tile 0 -> buf 0, tile 1 -> buf 1 (order pinned) ----
    {
        STAGE_A_F(0, 0); STAGE_B_F(0, 0); STAGE_B_B(0, 0); STAGE_A_B(0, 0);
        __builtin_amdgcn_sched_barrier(0);     // pin: tile-0 group before tile-1
        int sBe1 = 64;                          // tile 1: tap 0, k-offset 64
        STAGE_A_F(64, 1); STAGE_B_F(sBe1, 1); STAGE_B_B(sBe1, 1); STAGE_A_B(64, 1);
    }
    asm volatile("s_waitcnt lgkmcnt(0)" ::: "memory");   // rs writes visible
    asm volatile("s_waitcnt vmcnt(8)" ::: "memory");     // tile-0 chunks landed
    __builtin_amdgcn_s_barrier();

    frag_cd acc[8][4];                  // [mh*4+mf][nh*2+nf]
    #pragma unroll
    for (int i = 0; i < 8; i++)
        #pragma unroll
        for (int jx = 0; jx < 4; jx++)
            #pragma unroll
            for (int q = 0; q < 4; q++) acc[i][jx][q] = 0.f;

    frag_ab af[2][4], bfr0[2][2], bfr1[2][2];

#define LD_A(MH) { _Pragma("unroll") for (int mf = 0; mf < 4; mf++) { \
    af[0][mf] = *(const frag_ab*)(aB0 + (MH) * 8192 + mf * 2048); \
    af[1][mf] = *(const frag_ab*)(aB1 + (MH) * 8192 + mf * 2048); } }
#define LD_B_TO(BFA, NHH) { _Pragma("unroll") for (int nf = 0; nf < 2; nf++) { \
    BFA[0][nf] = *(const frag_ab*)(bB0 + (NHH) * 4096 + nf * 2048); \
    BFA[1][nf] = *(const frag_ab*)(bB1 + (NHH) * 4096 + nf * 2048); } }
#define MM(MH, NHH, BFA) { __builtin_amdgcn_s_setprio(1); \
    _Pragma("unroll") for (int mf = 0; mf < 4; mf++) \
    _Pragma("unroll") for (int nf = 0; nf < 2; nf++) { \
        acc[(MH)*4+mf][(NHH)*2+nf] = __builtin_amdgcn_mfma_f32_16x16x32_bf16( \
            af[0][mf], BFA[0][nf], acc[(MH)*4+mf][(NHH)*2+nf], 0, 0, 0); \
        acc[(MH)*4+mf][(NHH)*2+nf] = __builtin_amdgcn_mfma_f32_16x16x32_bf16( \
            af[1][mf], BFA[1][nf], acc[(MH)*4+mf][(NHH)*2+nf], 0, 0, 0); } \
    __builtin_amdgcn_s_setprio(0); }

    #pragma unroll 1
    for (int t = 0; t < 34; ++t) {
        int buf = t & 1;
        if ((t & 3) == 0 && t) {
            float rsc = *(const float*)(sm + RS_OFF + (t >> 2) * 4);
            #pragma unroll
            for (int i = 0; i < 8; i++)
                #pragma unroll
                for (int jx = 0; jx < 4; jx++)
                    #pragma unroll
                    for (int q = 0; q < 4; q++) acc[i][jx][q] *= rsc;
        }
        int tn = t + 2;                            // tile being staged (-> buf!)
        int sAe = tn * 64;
        int tapN = tn >> 2;
        int dyN = tapN / 3, dxN = tapN - 3 * dyN;
        int sBe = (dyN * WP + dxN) * NC + (tn & 3) * 64;

        const char* aB0 = sm + buf * 32768 + aRdRow + pA0;
        const char* aB1 = sm + buf * 32768 + aRdRow + pA1;
        const char* bB0 = sm + buf * 32768 + bRdRow + pA0 + BS_OFF;
        const char* bB1 = sm + buf * 32768 + bRdRow + pA1 + BS_OFF;

        // ph0: last read of S0 (A-front) + S1 (B-front); no staging
        LD_A(0); LD_B_TO(bfr0, 0); LD_B_TO(bfr1, 1);
        MM(0, 0, bfr0);
        __builtin_amdgcn_sched_barrier(0);
        __builtin_amdgcn_s_barrier();

        // ph1: last read of S2 (B-back, via bfr1 regs loaded ph0? no -- bfr1
        //      reads B-back rows in ph0!  B-back = pix {32-63,...} = nh*32+32?
        MM(0, 1, bfr1);
        STAGE_A_F(sAe, buf); STAGE_B_F(sBe, buf);
        __builtin_amdgcn_sched_barrier(0);
        __builtin_amdgcn_s_barrier();

        // ph2: last read of S3 (A-back)
        LD_A(1);
        MM(1, 1, bfr1);
        STAGE_B_B(sBe, buf);
        __builtin_amdgcn_sched_barrier(0);
        __builtin_amdgcn_s_barrier();

        // ph3: register-only MFMA; stage S3(t+2)
        MM(1, 0, bfr0);
        STAGE_A_B(sAe, buf);
        __builtin_amdgcn_sched_barrier(0);
        asm volatile("s_waitcnt vmcnt(8)" ::: "memory");   // tile t+1 landed
        __builtin_amdgcn_s_barrier();
    }

    // NOTE on region map above: bfr1 (nh=1 -> pix wn*64+32..63) IS the B-back
    // region S2, and it is read in ph0 together with bfr0.  So the last read
    // of BOTH B chunks is ph0, and S1/S2 staging at ph1/ph2 is safe a fortiori
    // (>= 1 full phase after last read).  A-front last read ph0 (LD_A(0)),
    // A-back last read ph2 (LD_A(1)) -> S3 staged at ph3.  All invariants hold.

    // ---- tail: tile 34 (buf 0, no staging, no intra-tile barriers) ----
    {
        const char* aB0 = sm + 0 * 32768 + aRdRow + pA0;
        const char* aB1 = sm + 0 * 32768 + aRdRow + pA1;
        const char* bB0 = sm + 0 * 32768 + bRdRow + pA0 + BS_OFF;
        const char* bB1 = sm + 0 * 32768 + bRdRow + pA1 + BS_OFF;
        LD_A(0); LD_B_TO(bfr0, 0); LD_B_TO(bfr1, 1);
        MM(0, 0, bfr0);
        MM(0, 1, bfr1);
        LD_A(1);
        MM(1, 1, bfr1);
        MM(1, 0, bfr0);
        __builtin_amdgcn_sched_barrier(0);
        asm volatile("s_waitcnt vmcnt(4)" ::: "memory");   // S0,S1(35) landed
        __builtin_amdgcn_s_barrier();
    }
    // ---- tail: tile 35 (buf 1) ----
    {
        const char* aB0 = sm + 1 * 32768 + aRdRow + pA0;
        const char* aB1 = sm + 1 * 32768 + aRdRow + pA1;
        const char* bB0 = sm + 1 * 32768 + bRdRow + pA0 + BS_OFF;
        const char* bB1 = sm + 1 * 32768 + bRdRow + pA1 + BS_OFF;
        LD_A(0); LD_B_TO(bfr0, 0);
        MM(0, 0, bfr0);
        __builtin_amdgcn_sched_barrier(0);
        asm volatile("s_waitcnt vmcnt(2)" ::: "memory");   // S2(35) landed
        __builtin_amdgcn_s_barrier();
        LD_B_TO(bfr1, 1);
        MM(0, 1, bfr1);
        __builtin_amdgcn_sched_barrier(0);
        asm volatile("s_waitcnt vmcnt(0)" ::: "memory");   // S3(35) landed
        __builtin_amdgcn_s_barrier();
        LD_A(1);
        MM(1, 1, bfr1);
        MM(1, 0, bfr0);
    }

    // epilogue: final scale by m[8], write C
    float m8 = *(const float*)(sm + RS_OFF + 9 * 4);
    int rqBase = lq * 4;
    #pragma unroll
    for (int mh = 0; mh < 2; mh++)
        #pragma unroll
        for (int mf = 0; mf < 4; mf++)
            #pragma unroll
            for (int nh = 0; nh < 2; nh++)
                #pragma unroll
                for (int nf = 0; nf < 2; nf++) {
                    int m = wm * 128 + mh * 64 + mf * 16 + rqBase;
                    int n = nt * 256 + wn * 64 + nh * 32 + nf * 16 + lm;
                    float* po = out + ((size_t)(b * 256 + m)) * 4096 + n;
                    frag_cd v = acc[mh * 4 + mf][nh * 2 + nf];
                    #pragma unroll
                    for (int q = 0; q < 4; q++) po[(size_t)q * 4096] = m8 * v[q];
                }
}

__global__ void diag_kernel(float* out) { out[threadIdx.x] = 12345.0f; }

extern "C" void kernel_launch(void* const* d_in, const int* in_sizes, int n_in,
                              void* d_out, int out_size, void* d_ws, size_t ws_size,
                              hipStream_t stream) {
    const float* inp = (const float*)d_in[0];
    const float* act = (const float*)d_in[1];
    const float* wgt = (const float*)d_in[2];
    float* out = (float*)d_out;

    size_t WT_OFF = 0;
    size_t XP_OFF = WT_ELEMS * sizeof(bf16);            // 1,179,648 (4K-aligned)
    size_t NEED  = XP_OFF + XP_ELEMS * sizeof(bf16);    // ~144 MB

    if (ws_size < NEED) {
        diag_kernel<<<1, 256, 0, stream>>>(out);
        return;
    }

    bf16* Wt = (bf16*)((char*)d_ws + WT_OFF);
    bf16* Xp = (bf16*)((char*)d_ws + XP_OFF);

    hipFuncSetAttribute((const void*)gemm_kernel,
                        hipFuncAttributeMaxDynamicSharedMemorySize, SMEM_BYTES);

    wt_kernel<<<NC, 256, 0, stream>>>(wgt, Wt);
    border_kernel<<<(NB * 260 * 32) / 256, 256, 0, stream>>>(Xp);
    pad_kernel<<<NB * NH * 4, 256, 0, stream>>>(inp, Xp);
    gemm_kernel<<<NB * 16, 512, SMEM_BYTES, stream>>>(Wt, act, Xp, out);
}